// Round 6
// baseline (543.276 us; speedup 1.0000x reference)
//
#include <hip/hip_runtime.h>

constexpr int kL = 2, kB = 2, kS = 128, kE = 512, kH = 8, kF = 2048;
constexpr float kScale = 0.125f; // D^-0.5, D=64

typedef __attribute__((ext_vector_type(8))) short s16x8;
typedef __attribute__((ext_vector_type(8))) _Float16 f16x8;
typedef __attribute__((ext_vector_type(4))) float f32x4;

__device__ __forceinline__ unsigned short f2h(float f) {
  union { _Float16 h; unsigned short u; } v;
  v.h = (_Float16)f;  // v_cvt_f16_f32, RNE
  return v.u;
}

__device__ __forceinline__ f32x4 mfma16(s16x8 a, s16x8 b, f32x4 c) {
  return __builtin_amdgcn_mfma_f32_16x16x32_f16(
      __builtin_bit_cast(f16x8, a), __builtin_bit_cast(f16x8, b), c, 0, 0, 0);
}

// ---------------- fp32 -> fp16 cast, 4 elems/thread ----------------
__global__ __launch_bounds__(256) void cast4_kernel(const float4* __restrict__ in,
                                                    unsigned short* __restrict__ out, int n4) {
  int i = blockIdx.x * 256 + threadIdx.x;
  if (i >= n4) return;
  float4 v = in[i];
  union { unsigned short u[4]; unsigned long long ll; } o;
  o.u[0] = f2h(v.x); o.u[1] = f2h(v.y); o.u[2] = f2h(v.z); o.u[3] = f2h(v.w);
  *(unsigned long long*)(out + (size_t)i * 4) = o.ll;
}

__global__ __launch_bounds__(256) void initx_kernel(const float* __restrict__ xin,
                                                    float* __restrict__ curf,
                                                    unsigned short* __restrict__ curb) {
  int i = blockIdx.x * 256 + threadIdx.x;
  float v = xin[i];
  curf[i] = v;
  curb[i] = f2h(v);
}

// ---------------- weight transpose + fp16 cast (batched descs) --------------
struct TDesc { const float* in; unsigned short* out; int K, N, tiles; };
struct TArgs { TDesc d[8]; int n; };

__global__ __launch_bounds__(256) void transpose_pack_kernel(TArgs ta) {
  int bid = blockIdx.x;
  int di = 0;
  while (di < ta.n && bid >= ta.d[di].tiles) { bid -= ta.d[di].tiles; ++di; }
  if (di >= ta.n) return;
  const float* in = ta.d[di].in;
  unsigned short* out = ta.d[di].out;
  int K = ta.d[di].K, N = ta.d[di].N;
  int tn = N >> 5;
  int n0 = (bid % tn) << 5, k0 = (bid / tn) << 5;
  __shared__ float lt[32][33];
  int tx = threadIdx.x & 31, ty = threadIdx.x >> 5;
#pragma unroll
  for (int r = 0; r < 4; ++r) {
    int kk = ty + r * 8;
    lt[kk][tx] = in[(size_t)(k0 + kk) * N + n0 + tx];
  }
  __syncthreads();
#pragma unroll
  for (int r = 0; r < 4; ++r) {
    int nn = ty + r * 8;
    out[(size_t)(n0 + nn) * K + k0 + tx] = f2h(lt[tx][nn]);
  }
}

// ---------------- generic 64x64-tile fp16 MFMA GEMM, C = A @ BT^T ------------
// Epilogues: 2: outf=acc+bias+resid   3: outb=fp16(gelu(acc+bias))
template <int EPI>
__global__ __launch_bounds__(256) void gemm64(
    const unsigned short* __restrict__ A, const unsigned short* __restrict__ BT,
    const unsigned short* __restrict__ BTalt,
    int N, int K, const float* __restrict__ bias, const float* __restrict__ resid,
    float* __restrict__ outf, unsigned short* __restrict__ outb) {
  const int m0 = blockIdx.x * 64, n0 = blockIdx.y * 64;
  if (BTalt && m0 >= 128) BT = BTalt;
  const int t = threadIdx.x, lane = t & 63, w = t >> 6;
  const int wm = w >> 1, wn = w & 1;
  const int l15 = lane & 15, l4 = lane >> 4;
  __shared__ __align__(16) short lsA[64 * 72];
  __shared__ __align__(16) short lsB[64 * 72];
  f32x4 acc[2][2] = {};
  for (int k0 = 0; k0 < K; k0 += 64) {
#pragma unroll
    for (int sg = 0; sg < 2; ++sg) {
      int idx = t + sg * 256;
      int row = idx >> 3, cb = (idx & 7) << 3;
      *(s16x8*)&lsA[row * 72 + cb] = *(const s16x8*)&A[(size_t)(m0 + row) * K + k0 + cb];
      *(s16x8*)&lsB[row * 72 + cb] = *(const s16x8*)&BT[(size_t)(n0 + row) * K + k0 + cb];
    }
    __syncthreads();
#pragma unroll
    for (int ks = 0; ks < 2; ++ks) {
      int lk = ks * 32 + l4 * 8;
      s16x8 a[2], bb[2];
#pragma unroll
      for (int mt = 0; mt < 2; ++mt) a[mt] = *(const s16x8*)&lsA[(wm * 32 + mt * 16 + l15) * 72 + lk];
#pragma unroll
      for (int nt = 0; nt < 2; ++nt) bb[nt] = *(const s16x8*)&lsB[(wn * 32 + nt * 16 + l15) * 72 + lk];
#pragma unroll
      for (int mt = 0; mt < 2; ++mt)
#pragma unroll
        for (int nt = 0; nt < 2; ++nt)
          acc[mt][nt] = mfma16(a[mt], bb[nt], acc[mt][nt]);
    }
    __syncthreads();
  }
#pragma unroll
  for (int mt = 0; mt < 2; ++mt) {
#pragma unroll
    for (int nt = 0; nt < 2; ++nt) {
#pragma unroll
      for (int r = 0; r < 4; ++r) {
        int row = m0 + wm * 32 + mt * 16 + l4 * 4 + r;
        int col = n0 + wn * 32 + nt * 16 + l15;
        float val = acc[mt][nt][r] + bias[col];
        size_t idx = (size_t)row * N + col;
        if (EPI == 2) outf[idx] = val + resid[idx];
        else {
          float g = 0.5f * val * (1.0f + erff(val * 0.70710678118654752f));
          outb[idx] = f2h(g);
        }
      }
    }
  }
}

// ---------------- fused q/k/v projection: one GEMM, col-routed epilogue ------
// BT = [WqT; WkT; WvT] as (3E x E) fp16 rows. grid (4, 24).
__global__ __launch_bounds__(256) void gemm_qkv(
    const unsigned short* __restrict__ A, const unsigned short* __restrict__ BT,
    const float* __restrict__ bq, const float* __restrict__ bk, const float* __restrict__ bv,
    float* __restrict__ qf, float* __restrict__ kf, float* __restrict__ vf) {
  const int m0 = blockIdx.x * 64, n0 = blockIdx.y * 64;
  const int t = threadIdx.x, lane = t & 63, w = t >> 6;
  const int wm = w >> 1, wn = w & 1;
  const int l15 = lane & 15, l4 = lane >> 4;
  __shared__ __align__(16) short lsA[64 * 72];
  __shared__ __align__(16) short lsB[64 * 72];
  f32x4 acc[2][2] = {};
  for (int k0 = 0; k0 < kE; k0 += 64) {
#pragma unroll
    for (int sg = 0; sg < 2; ++sg) {
      int idx = t + sg * 256;
      int row = idx >> 3, cb = (idx & 7) << 3;
      *(s16x8*)&lsA[row * 72 + cb] = *(const s16x8*)&A[(size_t)(m0 + row) * kE + k0 + cb];
      *(s16x8*)&lsB[row * 72 + cb] = *(const s16x8*)&BT[(size_t)(n0 + row) * kE + k0 + cb];
    }
    __syncthreads();
#pragma unroll
    for (int ks = 0; ks < 2; ++ks) {
      int lk = ks * 32 + l4 * 8;
      s16x8 a[2], bb[2];
#pragma unroll
      for (int mt = 0; mt < 2; ++mt) a[mt] = *(const s16x8*)&lsA[(wm * 32 + mt * 16 + l15) * 72 + lk];
#pragma unroll
      for (int nt = 0; nt < 2; ++nt) bb[nt] = *(const s16x8*)&lsB[(wn * 32 + nt * 16 + l15) * 72 + lk];
#pragma unroll
      for (int mt = 0; mt < 2; ++mt)
#pragma unroll
        for (int nt = 0; nt < 2; ++nt)
          acc[mt][nt] = mfma16(a[mt], bb[nt], acc[mt][nt]);
    }
    __syncthreads();
  }
  const int section = n0 >> 9;           // 0=q, 1=k, 2=v (64 | 512)
  const int nbase = n0 & (kE - 1);
  const float* bias = (section == 0) ? bq : (section == 1) ? bk : bv;
  float* outp = (section == 0) ? qf : (section == 1) ? kf : vf;
  const float oscale = (section == 0) ? kScale : 1.0f;
#pragma unroll
  for (int mt = 0; mt < 2; ++mt) {
#pragma unroll
    for (int nt = 0; nt < 2; ++nt) {
#pragma unroll
      for (int r = 0; r < 4; ++r) {
        int row = m0 + wm * 32 + mt * 16 + l4 * 4 + r;
        int col = nbase + wn * 32 + nt * 16 + l15;
        outp[(size_t)row * kE + col] = (acc[mt][nt][r] + bias[col]) * oscale;
      }
    }
  }
}

// ---------------- fused relation-GEMM + score reduce, 2 heads/block ----------
// block = (j, b, hp): heads h0=2hp, h0+1. C[i, 0:256] = [Ua(h0)|Ub(h0)|Ua(h1)|Ub(h1)]
// from rel[b,j,i,:] @ WrT rows, then scores[b,h,i,j] = s*sum_d (q'+Ua)(k+Ub)
__global__ __launch_bounds__(256) void score_kernel(
    const unsigned short* __restrict__ relb, const unsigned short* __restrict__ wrT,
    const float* __restrict__ qf, const float* __restrict__ kf,
    float* __restrict__ sc) {
  const int j = blockIdx.x, b = blockIdx.y, h0 = blockIdx.z * 2;
  const int t = threadIdx.x, lane = t & 63, w = t >> 6;
  const int l15 = lane & 15, l4 = lane >> 4;
  __shared__ __align__(16) short lsA[128 * 72];
  __shared__ __align__(16) short lsB[256 * 72];
  const unsigned short* Ab = relb + ((size_t)b * kS + j) * kS * kE;
  f32x4 acc[2][16] = {};
  for (int k0 = 0; k0 < kE; k0 += 64) {
#pragma unroll
    for (int sg = 0; sg < 4; ++sg) {
      int idx = t + sg * 256;
      int row = idx >> 3, cb = (idx & 7) << 3;
      *(s16x8*)&lsA[row * 72 + cb] = *(const s16x8*)&Ab[(size_t)row * kE + k0 + cb];
    }
#pragma unroll
    for (int sg = 0; sg < 8; ++sg) {
      int idx = t + sg * 256;
      int row = idx >> 3, cb = (idx & 7) << 3;
      int hh = h0 + (row >> 7), r = row & 127;
      int grow = (r < 64) ? (hh * 64 + r) : (kE + hh * 64 + r - 64);
      *(s16x8*)&lsB[row * 72 + cb] = *(const s16x8*)&wrT[(size_t)grow * kE + k0 + cb];
    }
    __syncthreads();
#pragma unroll
    for (int ks = 0; ks < 2; ++ks) {
      int lk = ks * 32 + l4 * 8;
      s16x8 a[2];
#pragma unroll
      for (int mt = 0; mt < 2; ++mt) a[mt] = *(const s16x8*)&lsA[(w * 32 + mt * 16 + l15) * 72 + lk];
#pragma unroll
      for (int nt = 0; nt < 16; ++nt) {
        s16x8 bb = *(const s16x8*)&lsB[(nt * 16 + l15) * 72 + lk];
        acc[0][nt] = mfma16(a[0], bb, acc[0][nt]);
        acc[1][nt] = mfma16(a[1], bb, acc[1][nt]);
      }
    }
    __syncthreads();
  }
#pragma unroll
  for (int hh = 0; hh < 2; ++hh) {
    const int h = h0 + hh;
    const float* krow = kf + ((size_t)b * kS + j) * kE + h * 64;
    float kv[4];
#pragma unroll
    for (int nt = 0; nt < 4; ++nt) kv[nt] = krow[nt * 16 + l15];
#pragma unroll
    for (int mt = 0; mt < 2; ++mt) {
#pragma unroll
      for (int r = 0; r < 4; ++r) {
        int i = w * 32 + mt * 16 + l4 * 4 + r;
        const float* qrow = qf + ((size_t)b * kS + i) * kE + h * 64;
        float p = 0.f;
#pragma unroll
        for (int nt = 0; nt < 4; ++nt) {
          float qv = qrow[nt * 16 + l15];
          p += (qv + acc[mt][hh * 8 + nt][r]) * (kv[nt] + acc[mt][hh * 8 + nt + 4][r]);
        }
#pragma unroll
        for (int o = 1; o < 16; o <<= 1) p += __shfl_xor(p, o, 16);
        if (l15 == 0) sc[(((size_t)b * kH + h) * kS + i) * kS + j] = kScale * p;
      }
    }
  }
}

// ---------------- fused softmax + PV: attn = softmax(sc) @ v -> fp16 ---------
__global__ __launch_bounds__(256) void softmax_pv_kernel(
    const float* __restrict__ sc, const float* __restrict__ vf,
    unsigned short* __restrict__ attnb) {
  const int i = blockIdx.x, b = blockIdx.y, t = threadIdx.x;
  const int lane = t & 63, w = t >> 6;
  __shared__ float lw[kH][kS];
#pragma unroll
  for (int sg = 0; sg < 4; ++sg) {
    int idx = t + sg * 256;
    int hh = idx >> 7, jj = idx & 127;
    lw[hh][jj] = sc[(((size_t)b * kH + hh) * kS + i) * kS + jj];
  }
  __syncthreads();
  // softmax: wave w handles rows 2w, 2w+1 (full 64-lane butterfly)
#pragma unroll
  for (int rr = 0; rr < 2; ++rr) {
    int h = w * 2 + rr;
    float v0 = lw[h][lane], v1 = lw[h][lane + 64];
    float m = fmaxf(v0, v1);
#pragma unroll
    for (int o = 32; o; o >>= 1) m = fmaxf(m, __shfl_xor(m, o));
    float e0 = expf(v0 - m), e1 = expf(v1 - m);
    float s = e0 + e1;
#pragma unroll
    for (int o = 32; o; o >>= 1) s += __shfl_xor(s, o);
    float inv = 1.0f / s;
    lw[h][lane] = e0 * inv;
    lw[h][lane + 64] = e1 * inv;
  }
  __syncthreads();
  const float* vb = vf + (size_t)b * kS * kE;
  float s0 = 0.f, s1 = 0.f;
  for (int jj = 0; jj < kS; ++jj) {
    s0 += lw[w][jj] * vb[(size_t)jj * kE + t];
    s1 += lw[w + 4][jj] * vb[(size_t)jj * kE + t + 256];
  }
  size_t o = ((size_t)b * kS + i) * kE;
  attnb[o + t] = f2h(s0);
  attnb[o + t + 256] = f2h(s1);
}

// ---------------- LayerNorm over E=512, writes fp32 + fp16 -------------------
__global__ __launch_bounds__(256) void ln_kernel(
    const float* __restrict__ in, const float* __restrict__ g, const float* __restrict__ bb,
    float* __restrict__ outf, unsigned short* __restrict__ outb) {
  int row = blockIdx.x, t = threadIdx.x, lane = t & 63, w = t >> 6;
  const float* p = in + (size_t)row * kE;
  float v0 = p[t], v1 = p[t + 256];
  float s = v0 + v1, q = v0 * v0 + v1 * v1;
#pragma unroll
  for (int o = 32; o; o >>= 1) { s += __shfl_xor(s, o); q += __shfl_xor(q, o); }
  __shared__ float rs[4], rq[4];
  if (lane == 0) { rs[w] = s; rq[w] = q; }
  __syncthreads();
  s = rs[0] + rs[1] + rs[2] + rs[3];
  q = rq[0] + rq[1] + rq[2] + rq[3];
  float mu = s * (1.0f / kE);
  float var = q * (1.0f / kE) - mu * mu;
  float inv = rsqrtf(var + 1e-5f);
  float o0 = (v0 - mu) * inv * g[t] + bb[t];
  float o1 = (v1 - mu) * inv * g[t + 256] + bb[t + 256];
  size_t base = (size_t)row * kE;
  outf[base + t] = o0; outf[base + t + 256] = o1;
  outb[base + t] = f2h(o0); outb[base + t + 256] = f2h(o1);
}

extern "C" void kernel_launch(void* const* d_in, const int* in_sizes, int n_in,
                              void* d_out, int out_size, void* d_ws, size_t ws_size,
                              hipStream_t stream) {
  (void)in_sizes; (void)n_in; (void)out_size; (void)ws_size;
  const float* x_in = (const float*)d_in[0];
  const float* rel  = (const float*)d_in[1];
  const float* Wq = (const float*)d_in[2];
  const float* bq = (const float*)d_in[3];
  const float* Wk = (const float*)d_in[4];
  const float* bk = (const float*)d_in[5];
  const float* Wv = (const float*)d_in[6];
  const float* bv = (const float*)d_in[7];
  const float* Wr = (const float*)d_in[8];
  const float* Wo = (const float*)d_in[9];
  const float* bo = (const float*)d_in[10];
  const float* W1 = (const float*)d_in[11];
  const float* b1 = (const float*)d_in[12];
  const float* W2 = (const float*)d_in[13];
  const float* b2 = (const float*)d_in[14];
  const float* ln1g = (const float*)d_in[15];
  const float* ln1b = (const float*)d_in[16];
  const float* ln2g = (const float*)d_in[17];
  const float* ln2b = (const float*)d_in[18];

  char* ws = (char*)d_ws;
  size_t off = 0;
  auto alloc = [&](size_t bytes) -> char* {
    char* p = ws + off;
    off += (bytes + 255) & ~(size_t)255;
    return p;
  };

  unsigned short* relb = (unsigned short*)alloc((size_t)kB * kS * kS * kE * 2);
  float* scores = (float*)alloc((size_t)kB * kH * kS * kS * 4);
  float* qf = (float*)alloc((size_t)kB * kS * kE * 4);
  float* kf = (float*)alloc((size_t)kB * kS * kE * 4);
  float* vf = (float*)alloc((size_t)kB * kS * kE * 4);
  float* curf = (float*)alloc((size_t)kB * kS * kE * 4);
  unsigned short* curb = (unsigned short*)alloc((size_t)kB * kS * kE * 2);
  float* tmp = (float*)alloc((size_t)kB * kS * kE * 4);
  unsigned short* h1b = (unsigned short*)alloc((size_t)kB * kS * kF * 2);
  unsigned short* attnb = (unsigned short*)alloc((size_t)kB * kS * kE * 2);
  unsigned short* wqkvT = (unsigned short*)alloc((size_t)3 * kE * kE * 2);  // [WqT;WkT;WvT]
  unsigned short* wrT = (unsigned short*)alloc((size_t)2 * kE * kE * 2);
  unsigned short* woT0 = (unsigned short*)alloc((size_t)kE * kE * 2);  // Wo[0] — batch 0
  unsigned short* woT1 = (unsigned short*)alloc((size_t)kE * kE * 2);  // Wo[1] — batch 1
  unsigned short* w1T = (unsigned short*)alloc((size_t)kF * kE * 2);
  unsigned short* w2T = (unsigned short*)alloc((size_t)kE * kF * 2);

  int n4 = kB * kS * kS * kE / 4;
  cast4_kernel<<<(n4 + 255) / 256, 256, 0, stream>>>((const float4*)rel, relb, n4);
  initx_kernel<<<kB * kS * kE / 256, 256, 0, stream>>>(x_in, curf, curb);

  const int t512 = (kE / 32) * (kE / 32);  // 256
  for (int l = 0; l < kL; ++l) {
    TArgs ta;
    ta.d[0] = { Wq + (size_t)l * kE * kE, wqkvT, kE, kE, t512 };
    ta.d[1] = { Wk + (size_t)l * kE * kE, wqkvT + (size_t)kE * kE, kE, kE, t512 };
    ta.d[2] = { Wv + (size_t)l * kE * kE, wqkvT + (size_t)2 * kE * kE, kE, kE, t512 };
    ta.d[3] = { Wr + (size_t)l * kE * 2 * kE, wrT, kE, 2 * kE, 2 * t512 };
    ta.d[4] = { W1 + (size_t)l * kE * kF, w1T, kE, kF, (kE / 32) * (kF / 32) };
    ta.d[5] = { W2 + (size_t)l * kF * kE, w2T, kF, kE, (kF / 32) * (kE / 32) };
    ta.n = 6;
    if (l == 0) {
      // Wo is NOT layer-indexed in the reference: (L,E,E) broadcast against
      // (B,S,E) with B==L means batch b uses Wo[b] in BOTH layers.
      ta.d[6] = { Wo, woT0, kE, kE, t512 };
      ta.d[7] = { Wo + (size_t)kE * kE, woT1, kE, kE, t512 };
      ta.n = 8;
    }
    int total_tiles = 0;
    for (int i = 0; i < ta.n; ++i) total_tiles += ta.d[i].tiles;
    transpose_pack_kernel<<<total_tiles, 256, 0, stream>>>(ta);

    gemm_qkv<<<dim3(4, 3 * kE / 64), 256, 0, stream>>>(
        curb, wqkvT, bq + (size_t)l * kE, bk + (size_t)l * kE, bv + (size_t)l * kE, qf, kf, vf);

    score_kernel<<<dim3(kS, kB, kH / 2), 256, 0, stream>>>(relb, wrT, qf, kf, scores);
    softmax_pv_kernel<<<dim3(kS, kB), 256, 0, stream>>>(scores, vf, attnb);

    // per-batch Wo selection: tiles with m0>=128 (batch 1) use woT1
    gemm64<2><<<dim3(4, kE / 64), 256, 0, stream>>>(attnb, woT0, woT1, kE, kE, bo + (size_t)l * kE, curf, tmp, nullptr);
    ln_kernel<<<kB * kS, 256, 0, stream>>>(tmp, ln1g + (size_t)l * kE, ln1b + (size_t)l * kE, curf, curb);

    gemm64<3><<<dim3(4, kF / 64), 256, 0, stream>>>(curb, w1T, nullptr, kF, kE, b1 + (size_t)l * kF, nullptr, nullptr, h1b);
    gemm64<2><<<dim3(4, kE / 64), 256, 0, stream>>>(h1b, w2T, nullptr, kE, kF, b2 + (size_t)l * kE, curf, tmp, nullptr);
    ln_kernel<<<kB * kS, 256, 0, stream>>>(tmp, ln2g + (size_t)l * kE, ln2b + (size_t)l * kE, curf, curb);
  }

  hipMemcpyAsync(d_out, curf, (size_t)kB * kS * kE * 4, hipMemcpyDeviceToDevice, stream);
}

// Round 7
// 476.226 us; speedup vs baseline: 1.1408x; 1.1408x over previous
//
#include <hip/hip_runtime.h>

constexpr int kL = 2, kB = 2, kS = 128, kE = 512, kH = 8, kF = 2048;
constexpr float kScale = 0.125f; // D^-0.5, D=64

typedef __attribute__((ext_vector_type(8))) short s16x8;
typedef __attribute__((ext_vector_type(8))) _Float16 f16x8;
typedef __attribute__((ext_vector_type(4))) float f32x4;

__device__ __forceinline__ unsigned short f2h(float f) {
  union { _Float16 h; unsigned short u; } v;
  v.h = (_Float16)f;  // v_cvt_f16_f32, RNE
  return v.u;
}

__device__ __forceinline__ f32x4 mfma16(s16x8 a, s16x8 b, f32x4 c) {
  return __builtin_amdgcn_mfma_f32_16x16x32_f16(
      __builtin_bit_cast(f16x8, a), __builtin_bit_cast(f16x8, b), c, 0, 0, 0);
}

// async global->LDS, 16B per lane (global addr per-lane; LDS dest = base+lane*16)
__device__ __forceinline__ void async16(void* lds, const void* g) {
  __builtin_amdgcn_global_load_lds(
      (const __attribute__((address_space(1))) unsigned int*)g,
      (__attribute__((address_space(3))) unsigned int*)lds, 16, 0, 0);
}

// ------- relation: fp32 -> fp16 cast + T2 swizzle (16B group g -> g^(row&7)) --
// 8 floats/thread -> one 16B group written at the swizzled slot.
__global__ __launch_bounds__(256) void cast_swz_kernel(const float* __restrict__ in,
                                                       unsigned short* __restrict__ out,
                                                       int nGroups) {
  int G = blockIdx.x * 256 + threadIdx.x;
  if (G >= nGroups) return;
  int row = G >> 6;          // 512 shorts per row -> 64 groups of 8
  int wdx = G & 63;
  int chunk = wdx >> 3, g = wdx & 7;
  int gs = g ^ (row & 7);
  const float4* src = (const float4*)(in + ((size_t)G << 3));
  float4 v0 = src[0], v1 = src[1];
  union { unsigned short u[8]; s16x8 v; } o;
  o.u[0] = f2h(v0.x); o.u[1] = f2h(v0.y); o.u[2] = f2h(v0.z); o.u[3] = f2h(v0.w);
  o.u[4] = f2h(v1.x); o.u[5] = f2h(v1.y); o.u[6] = f2h(v1.z); o.u[7] = f2h(v1.w);
  *(s16x8*)(out + (size_t)row * 512 + chunk * 64 + gs * 8) = o.v;
}

__global__ __launch_bounds__(256) void initx_kernel(const float* __restrict__ xin,
                                                    float* __restrict__ curf,
                                                    unsigned short* __restrict__ curb) {
  int i = blockIdx.x * 256 + threadIdx.x;
  float v = xin[i];
  curf[i] = v;
  curb[i] = f2h(v);
}

// ---------------- weight transpose + fp16 cast (batched descs) --------------
// swz: apply the T2 group swizzle on the output row (for wrT only).
struct TDesc { const float* in; unsigned short* out; int K, N, tiles, swz; };
struct TArgs { TDesc d[8]; int n; };

__global__ __launch_bounds__(256) void transpose_pack_kernel(TArgs ta) {
  int bid = blockIdx.x;
  int di = 0;
  while (di < ta.n && bid >= ta.d[di].tiles) { bid -= ta.d[di].tiles; ++di; }
  if (di >= ta.n) return;
  const float* in = ta.d[di].in;
  unsigned short* out = ta.d[di].out;
  int K = ta.d[di].K, N = ta.d[di].N, swz = ta.d[di].swz;
  int tn = N >> 5;
  int n0 = (bid % tn) << 5, k0 = (bid / tn) << 5;
  __shared__ float lt[32][33];
  int tx = threadIdx.x & 31, ty = threadIdx.x >> 5;
#pragma unroll
  for (int r = 0; r < 4; ++r) {
    int kk = ty + r * 8;
    lt[kk][tx] = in[(size_t)(k0 + kk) * N + n0 + tx];
  }
  __syncthreads();
#pragma unroll
  for (int r = 0; r < 4; ++r) {
    int nn = ty + r * 8;
    int n = n0 + nn;
    int col = k0 + tx;
    size_t o;
    if (swz) {
      o = (size_t)n * K + (col & ~63) + ((((col >> 3) & 7) ^ (n & 7)) << 3) + (col & 7);
    } else {
      o = (size_t)n * K + col;
    }
    out[o] = f2h(lt[tx][nn]);
  }
}

// ---------------- generic 64x64-tile fp16 MFMA GEMM, C = A @ BT^T ------------
// Epilogues: 2: outf=acc+bias+resid   3: outb=fp16(gelu(acc+bias))
template <int EPI>
__global__ __launch_bounds__(256) void gemm64(
    const unsigned short* __restrict__ A, const unsigned short* __restrict__ BT,
    const unsigned short* __restrict__ BTalt,
    int N, int K, const float* __restrict__ bias, const float* __restrict__ resid,
    float* __restrict__ outf, unsigned short* __restrict__ outb) {
  const int m0 = blockIdx.x * 64, n0 = blockIdx.y * 64;
  if (BTalt && m0 >= 128) BT = BTalt;
  const int t = threadIdx.x, lane = t & 63, w = t >> 6;
  const int wm = w >> 1, wn = w & 1;
  const int l15 = lane & 15, l4 = lane >> 4;
  __shared__ __align__(16) short lsA[64 * 72];
  __shared__ __align__(16) short lsB[64 * 72];
  f32x4 acc[2][2] = {};
  for (int k0 = 0; k0 < K; k0 += 64) {
#pragma unroll
    for (int sg = 0; sg < 2; ++sg) {
      int idx = t + sg * 256;
      int row = idx >> 3, cb = (idx & 7) << 3;
      *(s16x8*)&lsA[row * 72 + cb] = *(const s16x8*)&A[(size_t)(m0 + row) * K + k0 + cb];
      *(s16x8*)&lsB[row * 72 + cb] = *(const s16x8*)&BT[(size_t)(n0 + row) * K + k0 + cb];
    }
    __syncthreads();
#pragma unroll
    for (int ks = 0; ks < 2; ++ks) {
      int lk = ks * 32 + l4 * 8;
      s16x8 a[2], bb[2];
#pragma unroll
      for (int mt = 0; mt < 2; ++mt) a[mt] = *(const s16x8*)&lsA[(wm * 32 + mt * 16 + l15) * 72 + lk];
#pragma unroll
      for (int nt = 0; nt < 2; ++nt) bb[nt] = *(const s16x8*)&lsB[(wn * 32 + nt * 16 + l15) * 72 + lk];
#pragma unroll
      for (int mt = 0; mt < 2; ++mt)
#pragma unroll
        for (int nt = 0; nt < 2; ++nt)
          acc[mt][nt] = mfma16(a[mt], bb[nt], acc[mt][nt]);
    }
    __syncthreads();
  }
#pragma unroll
  for (int mt = 0; mt < 2; ++mt) {
#pragma unroll
    for (int nt = 0; nt < 2; ++nt) {
#pragma unroll
      for (int r = 0; r < 4; ++r) {
        int row = m0 + wm * 32 + mt * 16 + l4 * 4 + r;
        int col = n0 + wn * 32 + nt * 16 + l15;
        float val = acc[mt][nt][r] + bias[col];
        size_t idx = (size_t)row * N + col;
        if (EPI == 2) outf[idx] = val + resid[idx];
        else {
          float g = 0.5f * val * (1.0f + erff(val * 0.70710678118654752f));
          outb[idx] = f2h(g);
        }
      }
    }
  }
}

// ---------------- fused q/k/v projection: one GEMM, col-routed epilogue ------
// BT = [WqT; WkT; WvT] as (3E x E) fp16 rows. grid (4, 24).
__global__ __launch_bounds__(256) void gemm_qkv(
    const unsigned short* __restrict__ A, const unsigned short* __restrict__ BT,
    const float* __restrict__ bq, const float* __restrict__ bk, const float* __restrict__ bv,
    float* __restrict__ qf, float* __restrict__ kf, float* __restrict__ vf) {
  const int m0 = blockIdx.x * 64, n0 = blockIdx.y * 64;
  const int t = threadIdx.x, lane = t & 63, w = t >> 6;
  const int wm = w >> 1, wn = w & 1;
  const int l15 = lane & 15, l4 = lane >> 4;
  __shared__ __align__(16) short lsA[64 * 72];
  __shared__ __align__(16) short lsB[64 * 72];
  f32x4 acc[2][2] = {};
  for (int k0 = 0; k0 < kE; k0 += 64) {
#pragma unroll
    for (int sg = 0; sg < 2; ++sg) {
      int idx = t + sg * 256;
      int row = idx >> 3, cb = (idx & 7) << 3;
      *(s16x8*)&lsA[row * 72 + cb] = *(const s16x8*)&A[(size_t)(m0 + row) * kE + k0 + cb];
      *(s16x8*)&lsB[row * 72 + cb] = *(const s16x8*)&BT[(size_t)(n0 + row) * kE + k0 + cb];
    }
    __syncthreads();
#pragma unroll
    for (int ks = 0; ks < 2; ++ks) {
      int lk = ks * 32 + l4 * 8;
      s16x8 a[2], bb[2];
#pragma unroll
      for (int mt = 0; mt < 2; ++mt) a[mt] = *(const s16x8*)&lsA[(wm * 32 + mt * 16 + l15) * 72 + lk];
#pragma unroll
      for (int nt = 0; nt < 2; ++nt) bb[nt] = *(const s16x8*)&lsB[(wn * 32 + nt * 16 + l15) * 72 + lk];
#pragma unroll
      for (int mt = 0; mt < 2; ++mt)
#pragma unroll
        for (int nt = 0; nt < 2; ++nt)
          acc[mt][nt] = mfma16(a[mt], bb[nt], acc[mt][nt]);
    }
    __syncthreads();
  }
  const int section = n0 >> 9;           // 0=q, 1=k, 2=v
  const int nbase = n0 & (kE - 1);
  const float* bias = (section == 0) ? bq : (section == 1) ? bk : bv;
  float* outp = (section == 0) ? qf : (section == 1) ? kf : vf;
  const float oscale = (section == 0) ? kScale : 1.0f;
#pragma unroll
  for (int mt = 0; mt < 2; ++mt) {
#pragma unroll
    for (int nt = 0; nt < 2; ++nt) {
#pragma unroll
      for (int r = 0; r < 4; ++r) {
        int row = m0 + wm * 32 + mt * 16 + l4 * 4 + r;
        int col = nbase + wn * 32 + nt * 16 + l15;
        outp[(size_t)row * kE + col] = (acc[mt][nt][r] + bias[col]) * oscale;
      }
    }
  }
}

// ------- fused relation-GEMM + score reduce, global_load_lds + T2 swizzle ----
// block = (j, b, h). LDS linear [128][64] shorts; relb/wrT are pre-swizzled in
// global (group g of each 128B chunk at g^(row&7)); staging is a straight
// linear copy; ds_reads apply the same XOR.
__global__ __launch_bounds__(256) void score_kernel(
    const unsigned short* __restrict__ relb, const unsigned short* __restrict__ wrT,
    const float* __restrict__ qf, const float* __restrict__ kf,
    float* __restrict__ sc) {
  const int j = blockIdx.x, b = blockIdx.y, h = blockIdx.z;
  const int t = threadIdx.x, lane = t & 63, w = t >> 6;
  const int l15 = lane & 15, l4 = lane >> 4;
  __shared__ __align__(16) short lsA[128 * 64];
  __shared__ __align__(16) short lsB[128 * 64];
  const unsigned short* Ab = relb + ((size_t)b * kS + j) * kS * kE;
  const unsigned short* Bb0 = wrT + (size_t)(h * 64) * kE;        // Ua rows
  const unsigned short* Bb1 = wrT + (size_t)(kE + h * 64) * kE;   // Ub rows
  f32x4 acc[2][8] = {};
  for (int k0 = 0; k0 < kE; k0 += 64) {
#pragma unroll
    for (int it = 0; it < 4; ++it) {
      int c = it * 256 + t;           // 16B chunk index, 0..1023
      int row = c >> 3, g = c & 7;
      async16(&lsA[c * 8], Ab + (size_t)row * kE + k0 + g * 8);
      const unsigned short* bsrc = (row < 64)
          ? Bb0 + (size_t)row * kE + k0 + g * 8
          : Bb1 + (size_t)(row - 64) * kE + k0 + g * 8;
      async16(&lsB[c * 8], bsrc);
    }
    __syncthreads();   // drains vmcnt(0) before ds_read
#pragma unroll
    for (int ks = 0; ks < 2; ++ks) {
      s16x8 a[2], bb[8];
#pragma unroll
      for (int mt = 0; mt < 2; ++mt) {
        int row = w * 32 + mt * 16 + l15;
        int slot = (ks * 4 + l4) ^ (row & 7);
        a[mt] = *(const s16x8*)&lsA[row * 64 + slot * 8];
      }
#pragma unroll
      for (int nt = 0; nt < 8; ++nt) {
        int row = nt * 16 + l15;
        int slot = (ks * 4 + l4) ^ (row & 7);
        bb[nt] = *(const s16x8*)&lsB[row * 64 + slot * 8];
      }
#pragma unroll
      for (int mt = 0; mt < 2; ++mt)
#pragma unroll
        for (int nt = 0; nt < 8; ++nt)
          acc[mt][nt] = mfma16(a[mt], bb[nt], acc[mt][nt]);
    }
    __syncthreads();
  }
  const float* krow = kf + ((size_t)b * kS + j) * kE + h * 64;
  float kv[4];
#pragma unroll
  for (int nt = 0; nt < 4; ++nt) kv[nt] = krow[nt * 16 + l15];
#pragma unroll
  for (int mt = 0; mt < 2; ++mt) {
#pragma unroll
    for (int r = 0; r < 4; ++r) {
      int i = w * 32 + mt * 16 + l4 * 4 + r;
      const float* qrow = qf + ((size_t)b * kS + i) * kE + h * 64;
      float p = 0.f;
#pragma unroll
      for (int nt = 0; nt < 4; ++nt) {
        float qv = qrow[nt * 16 + l15];
        p += (qv + acc[mt][nt][r]) * (kv[nt] + acc[mt][nt + 4][r]);
      }
#pragma unroll
      for (int o = 1; o < 16; o <<= 1) p += __shfl_xor(p, o, 16);
      if (l15 == 0) sc[(((size_t)b * kH + h) * kS + i) * kS + j] = kScale * p;
    }
  }
}

// ---------------- fused softmax + PV: attn = softmax(sc) @ v -> fp16 ---------
__global__ __launch_bounds__(256) void softmax_pv_kernel(
    const float* __restrict__ sc, const float* __restrict__ vf,
    unsigned short* __restrict__ attnb) {
  const int i = blockIdx.x, b = blockIdx.y, t = threadIdx.x;
  const int lane = t & 63, w = t >> 6;
  __shared__ float lw[kH][kS];
#pragma unroll
  for (int sg = 0; sg < 4; ++sg) {
    int idx = t + sg * 256;
    int hh = idx >> 7, jj = idx & 127;
    lw[hh][jj] = sc[(((size_t)b * kH + hh) * kS + i) * kS + jj];
  }
  __syncthreads();
#pragma unroll
  for (int rr = 0; rr < 2; ++rr) {
    int h = w * 2 + rr;
    float v0 = lw[h][lane], v1 = lw[h][lane + 64];
    float m = fmaxf(v0, v1);
#pragma unroll
    for (int o = 32; o; o >>= 1) m = fmaxf(m, __shfl_xor(m, o));
    float e0 = expf(v0 - m), e1 = expf(v1 - m);
    float s = e0 + e1;
#pragma unroll
    for (int o = 32; o; o >>= 1) s += __shfl_xor(s, o);
    float inv = 1.0f / s;
    lw[h][lane] = e0 * inv;
    lw[h][lane + 64] = e1 * inv;
  }
  __syncthreads();
  const float* vb = vf + (size_t)b * kS * kE;
  float s0 = 0.f, s1 = 0.f;
  for (int jj = 0; jj < kS; ++jj) {
    s0 += lw[w][jj] * vb[(size_t)jj * kE + t];
    s1 += lw[w + 4][jj] * vb[(size_t)jj * kE + t + 256];
  }
  size_t o = ((size_t)b * kS + i) * kE;
  attnb[o + t] = f2h(s0);
  attnb[o + t + 256] = f2h(s1);
}

// ---------------- LayerNorm over E=512, writes fp32 + fp16 -------------------
__global__ __launch_bounds__(256) void ln_kernel(
    const float* __restrict__ in, const float* __restrict__ g, const float* __restrict__ bb,
    float* __restrict__ outf, unsigned short* __restrict__ outb) {
  int row = blockIdx.x, t = threadIdx.x, lane = t & 63, w = t >> 6;
  const float* p = in + (size_t)row * kE;
  float v0 = p[t], v1 = p[t + 256];
  float s = v0 + v1, q = v0 * v0 + v1 * v1;
#pragma unroll
  for (int o = 32; o; o >>= 1) { s += __shfl_xor(s, o); q += __shfl_xor(q, o); }
  __shared__ float rs[4], rq[4];
  if (lane == 0) { rs[w] = s; rq[w] = q; }
  __syncthreads();
  s = rs[0] + rs[1] + rs[2] + rs[3];
  q = rq[0] + rq[1] + rq[2] + rq[3];
  float mu = s * (1.0f / kE);
  float var = q * (1.0f / kE) - mu * mu;
  float inv = rsqrtf(var + 1e-5f);
  float o0 = (v0 - mu) * inv * g[t] + bb[t];
  float o1 = (v1 - mu) * inv * g[t + 256] + bb[t + 256];
  size_t base = (size_t)row * kE;
  outf[base + t] = o0; outf[base + t + 256] = o1;
  outb[base + t] = f2h(o0); outb[base + t + 256] = f2h(o1);
}

extern "C" void kernel_launch(void* const* d_in, const int* in_sizes, int n_in,
                              void* d_out, int out_size, void* d_ws, size_t ws_size,
                              hipStream_t stream) {
  (void)in_sizes; (void)n_in; (void)out_size; (void)ws_size;
  const float* x_in = (const float*)d_in[0];
  const float* rel  = (const float*)d_in[1];
  const float* Wq = (const float*)d_in[2];
  const float* bq = (const float*)d_in[3];
  const float* Wk = (const float*)d_in[4];
  const float* bk = (const float*)d_in[5];
  const float* Wv = (const float*)d_in[6];
  const float* bv = (const float*)d_in[7];
  const float* Wr = (const float*)d_in[8];
  const float* Wo = (const float*)d_in[9];
  const float* bo = (const float*)d_in[10];
  const float* W1 = (const float*)d_in[11];
  const float* b1 = (const float*)d_in[12];
  const float* W2 = (const float*)d_in[13];
  const float* b2 = (const float*)d_in[14];
  const float* ln1g = (const float*)d_in[15];
  const float* ln1b = (const float*)d_in[16];
  const float* ln2g = (const float*)d_in[17];
  const float* ln2b = (const float*)d_in[18];

  char* ws = (char*)d_ws;
  size_t off = 0;
  auto alloc = [&](size_t bytes) -> char* {
    char* p = ws + off;
    off += (bytes + 255) & ~(size_t)255;
    return p;
  };

  unsigned short* relb = (unsigned short*)alloc((size_t)kB * kS * kS * kE * 2);  // swizzled fp16
  float* scores = (float*)alloc((size_t)kB * kH * kS * kS * 4);
  float* qf = (float*)alloc((size_t)kB * kS * kE * 4);
  float* kf = (float*)alloc((size_t)kB * kS * kE * 4);
  float* vf = (float*)alloc((size_t)kB * kS * kE * 4);
  float* curf = (float*)alloc((size_t)kB * kS * kE * 4);
  unsigned short* curb = (unsigned short*)alloc((size_t)kB * kS * kE * 2);
  float* tmp = (float*)alloc((size_t)kB * kS * kE * 4);
  unsigned short* h1b = (unsigned short*)alloc((size_t)kB * kS * kF * 2);
  unsigned short* attnb = (unsigned short*)alloc((size_t)kB * kS * kE * 2);
  unsigned short* wqkvT = (unsigned short*)alloc((size_t)3 * kE * kE * 2);  // [WqT;WkT;WvT]
  unsigned short* wrT = (unsigned short*)alloc((size_t)2 * kE * kE * 2);    // swizzled
  unsigned short* woT0 = (unsigned short*)alloc((size_t)kE * kE * 2);  // Wo[0] — batch 0
  unsigned short* woT1 = (unsigned short*)alloc((size_t)kE * kE * 2);  // Wo[1] — batch 1
  unsigned short* w1T = (unsigned short*)alloc((size_t)kF * kE * 2);
  unsigned short* w2T = (unsigned short*)alloc((size_t)kE * kF * 2);

  int nGroups = kB * kS * kS * kE / 8;  // 2,097,152
  cast_swz_kernel<<<nGroups / 256, 256, 0, stream>>>(rel, relb, nGroups);
  initx_kernel<<<kB * kS * kE / 256, 256, 0, stream>>>(x_in, curf, curb);

  const int t512 = (kE / 32) * (kE / 32);  // 256
  for (int l = 0; l < kL; ++l) {
    TArgs ta;
    ta.d[0] = { Wq + (size_t)l * kE * kE, wqkvT, kE, kE, t512, 0 };
    ta.d[1] = { Wk + (size_t)l * kE * kE, wqkvT + (size_t)kE * kE, kE, kE, t512, 0 };
    ta.d[2] = { Wv + (size_t)l * kE * kE, wqkvT + (size_t)2 * kE * kE, kE, kE, t512, 0 };
    ta.d[3] = { Wr + (size_t)l * kE * 2 * kE, wrT, kE, 2 * kE, 2 * t512, 1 };  // swizzled
    ta.d[4] = { W1 + (size_t)l * kE * kF, w1T, kE, kF, (kE / 32) * (kF / 32), 0 };
    ta.d[5] = { W2 + (size_t)l * kF * kE, w2T, kF, kE, (kF / 32) * (kE / 32), 0 };
    ta.n = 6;
    if (l == 0) {
      // Wo is NOT layer-indexed in the reference: (L,E,E) broadcast against
      // (B,S,E) with B==L means batch b uses Wo[b] in BOTH layers.
      ta.d[6] = { Wo, woT0, kE, kE, t512, 0 };
      ta.d[7] = { Wo + (size_t)kE * kE, woT1, kE, kE, t512, 0 };
      ta.n = 8;
    }
    int total_tiles = 0;
    for (int i = 0; i < ta.n; ++i) total_tiles += ta.d[i].tiles;
    transpose_pack_kernel<<<total_tiles, 256, 0, stream>>>(ta);

    gemm_qkv<<<dim3(4, 3 * kE / 64), 256, 0, stream>>>(
        curb, wqkvT, bq + (size_t)l * kE, bk + (size_t)l * kE, bv + (size_t)l * kE, qf, kf, vf);

    score_kernel<<<dim3(kS, kB, kH), 256, 0, stream>>>(relb, wrT, qf, kf, scores);
    softmax_pv_kernel<<<dim3(kS, kB), 256, 0, stream>>>(scores, vf, attnb);

    // per-batch Wo selection: tiles with m0>=128 (batch 1) use woT1
    gemm64<2><<<dim3(4, kE / 64), 256, 0, stream>>>(attnb, woT0, woT1, kE, kE, bo + (size_t)l * kE, curf, tmp, nullptr);
    ln_kernel<<<kB * kS, 256, 0, stream>>>(tmp, ln1g + (size_t)l * kE, ln1b + (size_t)l * kE, curf, curb);

    gemm64<3><<<dim3(4, kF / 64), 256, 0, stream>>>(curb, w1T, nullptr, kF, kE, b1 + (size_t)l * kF, nullptr, nullptr, h1b);
    gemm64<2><<<dim3(4, kE / 64), 256, 0, stream>>>(h1b, w2T, nullptr, kE, kF, b2 + (size_t)l * kE, curf, tmp, nullptr);
    ln_kernel<<<kB * kS, 256, 0, stream>>>(tmp, ln2g + (size_t)l * kE, ln2b + (size_t)l * kE, curf, curb);
  }

  hipMemcpyAsync(d_out, curf, (size_t)kB * kS * kE * 4, hipMemcpyDeviceToDevice, stream);
}

// Round 8
// 389.619 us; speedup vs baseline: 1.3944x; 1.2223x over previous
//
#include <hip/hip_runtime.h>

constexpr int kL = 2, kB = 2, kS = 128, kE = 512, kH = 8, kF = 2048;
constexpr float kScale = 0.125f; // D^-0.5, D=64
constexpr float kInvE = 1.0f / kE;

typedef __attribute__((ext_vector_type(8))) short s16x8;
typedef __attribute__((ext_vector_type(8))) _Float16 f16x8;
typedef __attribute__((ext_vector_type(4))) float f32x4;

__device__ __forceinline__ unsigned short f2h(float f) {
  union { _Float16 h; unsigned short u; } v;
  v.h = (_Float16)f;
  return v.u;
}

__device__ __forceinline__ f32x4 mfma16(s16x8 a, s16x8 b, f32x4 c) {
  return __builtin_amdgcn_mfma_f32_16x16x32_f16(
      __builtin_bit_cast(f16x8, a), __builtin_bit_cast(f16x8, b), c, 0, 0, 0);
}

__device__ __forceinline__ void async16(void* lds, const void* g) {
  __builtin_amdgcn_global_load_lds(
      (const __attribute__((address_space(1))) unsigned int*)g,
      (__attribute__((address_space(3))) unsigned int*)lds, 16, 0, 0);
}

// stats layout per stage: [0..255]=sum, [256..511]=sumsq. stages: 2l=LN1(l), 2l+1=LN2(l)
__device__ __forceinline__ void ln_mu_inv(const float* st, int row, float& mu, float& inv) {
  float s = st[row], q = st[256 + row];
  mu = s * kInvE;
  inv = rsqrtf(q * kInvE - mu * mu + 1e-5f);
}

// stage one 8-col fp16 LDS group from fp32 src applying LN
__device__ __forceinline__ void stage_ln_row(short* lds, const float* src,
                                             const float* st, const float* g, const float* bb,
                                             int row, int colbase) {
  float mu, inv;
  ln_mu_inv(st, row, mu, inv);
  const float4* p = (const float4*)(src + (size_t)row * kE + colbase);
  float4 v0 = p[0], v1 = p[1];
  const float4* gp = (const float4*)(g + colbase);
  float4 g0 = gp[0], g1 = gp[1];
  const float4* bp = (const float4*)(bb + colbase);
  float4 b0 = bp[0], b1 = bp[1];
  union { unsigned short u[8]; s16x8 v; } o;
  o.u[0] = f2h((v0.x - mu) * inv * g0.x + b0.x);
  o.u[1] = f2h((v0.y - mu) * inv * g0.y + b0.y);
  o.u[2] = f2h((v0.z - mu) * inv * g0.z + b0.z);
  o.u[3] = f2h((v0.w - mu) * inv * g0.w + b0.w);
  o.u[4] = f2h((v1.x - mu) * inv * g1.x + b1.x);
  o.u[5] = f2h((v1.y - mu) * inv * g1.y + b1.y);
  o.u[6] = f2h((v1.z - mu) * inv * g1.z + b1.z);
  o.u[7] = f2h((v1.w - mu) * inv * g1.w + b1.w);
  *(s16x8*)lds = o.v;
}

// ------- relation: fp32 -> fp16 cast + T2 swizzle (16B group g -> g^(row&7)) --
__global__ __launch_bounds__(256) void cast_swz_kernel(const float* __restrict__ in,
                                                       unsigned short* __restrict__ out,
                                                       int nGroups) {
  int G = blockIdx.x * 256 + threadIdx.x;
  if (G >= nGroups) return;
  int row = G >> 6;
  int wdx = G & 63;
  int chunk = wdx >> 3, g = wdx & 7;
  int gs = g ^ (row & 7);
  const float4* src = (const float4*)(in + ((size_t)G << 3));
  float4 v0 = src[0], v1 = src[1];
  union { unsigned short u[8]; s16x8 v; } o;
  o.u[0] = f2h(v0.x); o.u[1] = f2h(v0.y); o.u[2] = f2h(v0.z); o.u[3] = f2h(v0.w);
  o.u[4] = f2h(v1.x); o.u[5] = f2h(v1.y); o.u[6] = f2h(v1.z); o.u[7] = f2h(v1.w);
  *(s16x8*)(out + (size_t)row * 512 + chunk * 64 + gs * 8) = o.v;
}

// initial x cast + zero the LN-stats buffer (4 stages x 512 floats)
__global__ __launch_bounds__(256) void initx_kernel(const float* __restrict__ xin,
                                                    unsigned short* __restrict__ curb,
                                                    float* __restrict__ stats) {
  int i = blockIdx.x * 256 + threadIdx.x;
  curb[i] = f2h(xin[i]);
  if (i < 4 * 512) stats[i] = 0.f;
}

// ---------------- weight transpose + fp16 cast (all layers, one launch) ------
struct TDesc { const float* in; unsigned short* out; int K, N, tiles, swz; };
struct TArgs { TDesc d[14]; int n; };

__global__ __launch_bounds__(256) void transpose_pack_kernel(TArgs ta) {
  int bid = blockIdx.x;
  int di = 0;
  while (di < ta.n && bid >= ta.d[di].tiles) { bid -= ta.d[di].tiles; ++di; }
  if (di >= ta.n) return;
  const float* in = ta.d[di].in;
  unsigned short* out = ta.d[di].out;
  int K = ta.d[di].K, N = ta.d[di].N, swz = ta.d[di].swz;
  int tn = N >> 5;
  int n0 = (bid % tn) << 5, k0 = (bid / tn) << 5;
  __shared__ float lt[32][33];
  int tx = threadIdx.x & 31, ty = threadIdx.x >> 5;
#pragma unroll
  for (int r = 0; r < 4; ++r) {
    int kk = ty + r * 8;
    lt[kk][tx] = in[(size_t)(k0 + kk) * N + n0 + tx];
  }
  __syncthreads();
#pragma unroll
  for (int r = 0; r < 4; ++r) {
    int nn = ty + r * 8;
    int n = n0 + nn;
    int col = k0 + tx;
    size_t o;
    if (swz) {
      o = (size_t)n * K + (col & ~63) + ((((col >> 3) & 7) ^ (n & 7)) << 3) + (col & 7);
    } else {
      o = (size_t)n * K + col;
    }
    out[o] = f2h(lt[tx][nn]);
  }
}

// ---------------- fused q/k/v projection (optionally LN-applying A-stage) ----
template <int LN>
__global__ __launch_bounds__(256) void gemm_qkv(
    const unsigned short* __restrict__ Ah, const float* __restrict__ Af,
    const float* __restrict__ st, const float* __restrict__ gln, const float* __restrict__ bln,
    const unsigned short* __restrict__ BT,
    const float* __restrict__ bq, const float* __restrict__ bk, const float* __restrict__ bv,
    float* __restrict__ qf, float* __restrict__ kf, float* __restrict__ vf) {
  const int m0 = blockIdx.x * 64, n0 = blockIdx.y * 64;
  const int t = threadIdx.x, lane = t & 63, w = t >> 6;
  const int wm = w >> 1, wn = w & 1;
  const int l15 = lane & 15, l4 = lane >> 4;
  __shared__ __align__(16) short lsA[64 * 72];
  __shared__ __align__(16) short lsB[64 * 72];
  f32x4 acc[2][2] = {};
  for (int k0 = 0; k0 < kE; k0 += 64) {
#pragma unroll
    for (int sg = 0; sg < 2; ++sg) {
      int idx = t + sg * 256;
      int row = idx >> 3, cb = (idx & 7) << 3;
      if (LN) stage_ln_row(&lsA[row * 72 + cb], Af, st, gln, bln, m0 + row, k0 + cb);
      else *(s16x8*)&lsA[row * 72 + cb] = *(const s16x8*)&Ah[(size_t)(m0 + row) * kE + k0 + cb];
      *(s16x8*)&lsB[row * 72 + cb] = *(const s16x8*)&BT[(size_t)(n0 + row) * kE + k0 + cb];
    }
    __syncthreads();
#pragma unroll
    for (int ks = 0; ks < 2; ++ks) {
      int lk = ks * 32 + l4 * 8;
      s16x8 a[2], bb[2];
#pragma unroll
      for (int mt = 0; mt < 2; ++mt) a[mt] = *(const s16x8*)&lsA[(wm * 32 + mt * 16 + l15) * 72 + lk];
#pragma unroll
      for (int nt = 0; nt < 2; ++nt) bb[nt] = *(const s16x8*)&lsB[(wn * 32 + nt * 16 + l15) * 72 + lk];
#pragma unroll
      for (int mt = 0; mt < 2; ++mt)
#pragma unroll
        for (int nt = 0; nt < 2; ++nt)
          acc[mt][nt] = mfma16(a[mt], bb[nt], acc[mt][nt]);
    }
    __syncthreads();
  }
  const int section = n0 >> 9;           // 0=q, 1=k, 2=v
  const int nbase = n0 & (kE - 1);
  const float* bias = (section == 0) ? bq : (section == 1) ? bk : bv;
  float* outp = (section == 0) ? qf : (section == 1) ? kf : vf;
  const float oscale = (section == 0) ? kScale : 1.0f;
#pragma unroll
  for (int mt = 0; mt < 2; ++mt)
#pragma unroll
    for (int nt = 0; nt < 2; ++nt)
#pragma unroll
      for (int r = 0; r < 4; ++r) {
        int row = m0 + wm * 32 + mt * 16 + l4 * 4 + r;
        int col = nbase + wn * 32 + nt * 16 + l15;
        outp[(size_t)row * kE + col] = (acc[mt][nt][r] + bias[col]) * oscale;
      }
}

// ---------------- Wo GEMM + residual + LN1-stats accumulation ----------------
// LNSRC=0: resid = residf[idx] (x_in). LNSRC=1: resid = LN(prevt, stIn, gIn, bIn).
template <int LNSRC>
__global__ __launch_bounds__(256) void gemm_wo(
    const unsigned short* __restrict__ A, const unsigned short* __restrict__ BT0,
    const unsigned short* __restrict__ BT1, const float* __restrict__ bias,
    const float* __restrict__ residf, const float* __restrict__ prevt,
    const float* __restrict__ stIn, const float* __restrict__ gIn, const float* __restrict__ bIn,
    float* __restrict__ outf, float* __restrict__ stOut) {
  const int m0 = blockIdx.x * 64, n0 = blockIdx.y * 64;
  const unsigned short* BT = (m0 >= 128) ? BT1 : BT0;
  const int t = threadIdx.x, lane = t & 63, w = t >> 6;
  const int wm = w >> 1, wn = w & 1;
  const int l15 = lane & 15, l4 = lane >> 4;
  __shared__ __align__(16) short lsA[64 * 72];
  __shared__ __align__(16) short lsB[64 * 72];
  f32x4 acc[2][2] = {};
  for (int k0 = 0; k0 < kE; k0 += 64) {
#pragma unroll
    for (int sg = 0; sg < 2; ++sg) {
      int idx = t + sg * 256;
      int row = idx >> 3, cb = (idx & 7) << 3;
      *(s16x8*)&lsA[row * 72 + cb] = *(const s16x8*)&A[(size_t)(m0 + row) * kE + k0 + cb];
      *(s16x8*)&lsB[row * 72 + cb] = *(const s16x8*)&BT[(size_t)(n0 + row) * kE + k0 + cb];
    }
    __syncthreads();
#pragma unroll
    for (int ks = 0; ks < 2; ++ks) {
      int lk = ks * 32 + l4 * 8;
      s16x8 a[2], bb[2];
#pragma unroll
      for (int mt = 0; mt < 2; ++mt) a[mt] = *(const s16x8*)&lsA[(wm * 32 + mt * 16 + l15) * 72 + lk];
#pragma unroll
      for (int nt = 0; nt < 2; ++nt) bb[nt] = *(const s16x8*)&lsB[(wn * 32 + nt * 16 + l15) * 72 + lk];
#pragma unroll
      for (int mt = 0; mt < 2; ++mt)
#pragma unroll
        for (int nt = 0; nt < 2; ++nt)
          acc[mt][nt] = mfma16(a[mt], bb[nt], acc[mt][nt]);
    }
    __syncthreads();
  }
  float ov[2][2][4];
#pragma unroll
  for (int mt = 0; mt < 2; ++mt)
#pragma unroll
    for (int nt = 0; nt < 2; ++nt)
#pragma unroll
      for (int r = 0; r < 4; ++r) {
        int row = m0 + wm * 32 + mt * 16 + l4 * 4 + r;
        int col = n0 + wn * 32 + nt * 16 + l15;
        size_t idx = (size_t)row * kE + col;
        float val = acc[mt][nt][r] + bias[col];
        float x;
        if (LNSRC == 0) x = residf[idx];
        else {
          float mu, inv;
          ln_mu_inv(stIn, row, mu, inv);
          x = (prevt[idx] - mu) * inv * gIn[col] + bIn[col];
        }
        float ot = val + x;
        outf[idx] = ot;
        ov[mt][nt][r] = ot;
      }
  // per-row (sum, sumsq) partials -> atomics
#pragma unroll
  for (int mt = 0; mt < 2; ++mt)
#pragma unroll
    for (int r = 0; r < 4; ++r) {
      float sp = ov[mt][0][r] + ov[mt][1][r];
      float qp = ov[mt][0][r] * ov[mt][0][r] + ov[mt][1][r] * ov[mt][1][r];
#pragma unroll
      for (int o = 1; o < 16; o <<= 1) { sp += __shfl_xor(sp, o, 16); qp += __shfl_xor(qp, o, 16); }
      if (l15 == 0) {
        int row = m0 + wm * 32 + mt * 16 + l4 * 4 + r;
        atomicAdd(&stOut[row], sp);
        atomicAdd(&stOut[256 + row], qp);
      }
    }
}

// ---------------- FFN1: A = LN(tmp1) staged on the fly; GELU -> fp16 ---------
__global__ __launch_bounds__(256) void gemm_ffn1(
    const float* __restrict__ Af, const float* __restrict__ st,
    const float* __restrict__ gln, const float* __restrict__ bln,
    const unsigned short* __restrict__ BT, const float* __restrict__ bias,
    unsigned short* __restrict__ outb) {
  const int m0 = blockIdx.x * 64, n0 = blockIdx.y * 64;
  const int t = threadIdx.x, lane = t & 63, w = t >> 6;
  const int wm = w >> 1, wn = w & 1;
  const int l15 = lane & 15, l4 = lane >> 4;
  __shared__ __align__(16) short lsA[64 * 72];
  __shared__ __align__(16) short lsB[64 * 72];
  f32x4 acc[2][2] = {};
  for (int k0 = 0; k0 < kE; k0 += 64) {
#pragma unroll
    for (int sg = 0; sg < 2; ++sg) {
      int idx = t + sg * 256;
      int row = idx >> 3, cb = (idx & 7) << 3;
      stage_ln_row(&lsA[row * 72 + cb], Af, st, gln, bln, m0 + row, k0 + cb);
      *(s16x8*)&lsB[row * 72 + cb] = *(const s16x8*)&BT[(size_t)(n0 + row) * kE + k0 + cb];
    }
    __syncthreads();
#pragma unroll
    for (int ks = 0; ks < 2; ++ks) {
      int lk = ks * 32 + l4 * 8;
      s16x8 a[2], bb[2];
#pragma unroll
      for (int mt = 0; mt < 2; ++mt) a[mt] = *(const s16x8*)&lsA[(wm * 32 + mt * 16 + l15) * 72 + lk];
#pragma unroll
      for (int nt = 0; nt < 2; ++nt) bb[nt] = *(const s16x8*)&lsB[(wn * 32 + nt * 16 + l15) * 72 + lk];
#pragma unroll
      for (int mt = 0; mt < 2; ++mt)
#pragma unroll
        for (int nt = 0; nt < 2; ++nt)
          acc[mt][nt] = mfma16(a[mt], bb[nt], acc[mt][nt]);
    }
    __syncthreads();
  }
#pragma unroll
  for (int mt = 0; mt < 2; ++mt)
#pragma unroll
    for (int nt = 0; nt < 2; ++nt)
#pragma unroll
      for (int r = 0; r < 4; ++r) {
        int row = m0 + wm * 32 + mt * 16 + l4 * 4 + r;
        int col = n0 + wn * 32 + nt * 16 + l15;
        float val = acc[mt][nt][r] + bias[col];
        float g = 0.5f * val * (1.0f + erff(val * 0.70710678118654752f));
        outb[(size_t)row * kF + col] = f2h(g);
      }
}

// ---------------- FFN2: +resid (recomputed LN1) + LN2-stats ------------------
__global__ __launch_bounds__(256) void gemm_ffn2(
    const unsigned short* __restrict__ A, const unsigned short* __restrict__ BT,
    const float* __restrict__ bias, const float* __restrict__ tmp1,
    const float* __restrict__ stIn, const float* __restrict__ gIn, const float* __restrict__ bIn,
    float* __restrict__ outf, float* __restrict__ stOut) {
  const int m0 = blockIdx.x * 64, n0 = blockIdx.y * 64;
  const int t = threadIdx.x, lane = t & 63, w = t >> 6;
  const int wm = w >> 1, wn = w & 1;
  const int l15 = lane & 15, l4 = lane >> 4;
  __shared__ __align__(16) short lsA[64 * 72];
  __shared__ __align__(16) short lsB[64 * 72];
  f32x4 acc[2][2] = {};
  for (int k0 = 0; k0 < kF; k0 += 64) {
#pragma unroll
    for (int sg = 0; sg < 2; ++sg) {
      int idx = t + sg * 256;
      int row = idx >> 3, cb = (idx & 7) << 3;
      *(s16x8*)&lsA[row * 72 + cb] = *(const s16x8*)&A[(size_t)(m0 + row) * kF + k0 + cb];
      *(s16x8*)&lsB[row * 72 + cb] = *(const s16x8*)&BT[(size_t)(n0 + row) * kF + k0 + cb];
    }
    __syncthreads();
#pragma unroll
    for (int ks = 0; ks < 2; ++ks) {
      int lk = ks * 32 + l4 * 8;
      s16x8 a[2], bb[2];
#pragma unroll
      for (int mt = 0; mt < 2; ++mt) a[mt] = *(const s16x8*)&lsA[(wm * 32 + mt * 16 + l15) * 72 + lk];
#pragma unroll
      for (int nt = 0; nt < 2; ++nt) bb[nt] = *(const s16x8*)&lsB[(wn * 32 + nt * 16 + l15) * 72 + lk];
#pragma unroll
      for (int mt = 0; mt < 2; ++mt)
#pragma unroll
        for (int nt = 0; nt < 2; ++nt)
          acc[mt][nt] = mfma16(a[mt], bb[nt], acc[mt][nt]);
    }
    __syncthreads();
  }
  float ov[2][2][4];
#pragma unroll
  for (int mt = 0; mt < 2; ++mt)
#pragma unroll
    for (int nt = 0; nt < 2; ++nt)
#pragma unroll
      for (int r = 0; r < 4; ++r) {
        int row = m0 + wm * 32 + mt * 16 + l4 * 4 + r;
        int col = n0 + wn * 32 + nt * 16 + l15;
        size_t idx = (size_t)row * kE + col;
        float val = acc[mt][nt][r] + bias[col];
        float mu, inv;
        ln_mu_inv(stIn, row, mu, inv);
        float x1 = (tmp1[idx] - mu) * inv * gIn[col] + bIn[col];
        float ot = val + x1;
        outf[idx] = ot;
        ov[mt][nt][r] = ot;
      }
#pragma unroll
  for (int mt = 0; mt < 2; ++mt)
#pragma unroll
    for (int r = 0; r < 4; ++r) {
      float sp = ov[mt][0][r] + ov[mt][1][r];
      float qp = ov[mt][0][r] * ov[mt][0][r] + ov[mt][1][r] * ov[mt][1][r];
#pragma unroll
      for (int o = 1; o < 16; o <<= 1) { sp += __shfl_xor(sp, o, 16); qp += __shfl_xor(qp, o, 16); }
      if (l15 == 0) {
        int row = m0 + wm * 32 + mt * 16 + l4 * 4 + r;
        atomicAdd(&stOut[row], sp);
        atomicAdd(&stOut[256 + row], qp);
      }
    }
}

// ------- fused relation-GEMM + score reduce (gload_lds, loop-carried ptrs) ---
__global__ __launch_bounds__(256) void score_kernel(
    const unsigned short* __restrict__ relb, const unsigned short* __restrict__ wrT,
    const float* __restrict__ qf, const float* __restrict__ kf,
    float* __restrict__ sc) {
  const int j = blockIdx.x, b = blockIdx.y, h = blockIdx.z;
  const int t = threadIdx.x, lane = t & 63, w = t >> 6;
  const int l15 = lane & 15, l4 = lane >> 4;
  __shared__ __align__(16) short lsA[128 * 64];
  __shared__ __align__(16) short lsB[128 * 64];
  const unsigned short* Ab = relb + ((size_t)b * kS + j) * kS * kE;
  const unsigned short* Bb0 = wrT + (size_t)(h * 64) * kE;
  const unsigned short* Bb1 = wrT + (size_t)(kE + h * 64) * kE;
  // loop-carried staging pointers (address calc hoisted out of the K-loop)
  const unsigned short* aptr[4];
  const unsigned short* bptr[4];
  short* alds[4];
  short* blds[4];
#pragma unroll
  for (int it = 0; it < 4; ++it) {
    int c = it * 256 + t;
    int row = c >> 3, g = c & 7;
    aptr[it] = Ab + (size_t)row * kE + g * 8;
    bptr[it] = (row < 64) ? Bb0 + (size_t)row * kE + g * 8
                          : Bb1 + (size_t)(row - 64) * kE + g * 8;
    alds[it] = &lsA[c * 8];
    blds[it] = &lsB[c * 8];
  }
  f32x4 acc[2][8] = {};
  for (int k0 = 0; k0 < kE; k0 += 64) {
#pragma unroll
    for (int it = 0; it < 4; ++it) {
      async16(alds[it], aptr[it]);
      async16(blds[it], bptr[it]);
      aptr[it] += 64;
      bptr[it] += 64;
    }
    __syncthreads();
#pragma unroll
    for (int ks = 0; ks < 2; ++ks) {
      s16x8 a[2], bb[8];
#pragma unroll
      for (int mt = 0; mt < 2; ++mt) {
        int row = w * 32 + mt * 16 + l15;
        int slot = (ks * 4 + l4) ^ (row & 7);
        a[mt] = *(const s16x8*)&lsA[row * 64 + slot * 8];
      }
#pragma unroll
      for (int nt = 0; nt < 8; ++nt) {
        int row = nt * 16 + l15;
        int slot = (ks * 4 + l4) ^ (row & 7);
        bb[nt] = *(const s16x8*)&lsB[row * 64 + slot * 8];
      }
#pragma unroll
      for (int mt = 0; mt < 2; ++mt)
#pragma unroll
        for (int nt = 0; nt < 8; ++nt)
          acc[mt][nt] = mfma16(a[mt], bb[nt], acc[mt][nt]);
    }
    __syncthreads();
  }
  const float* krow = kf + ((size_t)b * kS + j) * kE + h * 64;
  float kv[4];
#pragma unroll
  for (int nt = 0; nt < 4; ++nt) kv[nt] = krow[nt * 16 + l15];
#pragma unroll
  for (int mt = 0; mt < 2; ++mt)
#pragma unroll
    for (int r = 0; r < 4; ++r) {
      int i = w * 32 + mt * 16 + l4 * 4 + r;
      const float* qrow = qf + ((size_t)b * kS + i) * kE + h * 64;
      float p = 0.f;
#pragma unroll
      for (int nt = 0; nt < 4; ++nt) {
        float qv = qrow[nt * 16 + l15];
        p += (qv + acc[mt][nt][r]) * (kv[nt] + acc[mt][nt + 4][r]);
      }
#pragma unroll
      for (int o = 1; o < 16; o <<= 1) p += __shfl_xor(p, o, 16);
      if (l15 == 0) sc[(((size_t)b * kH + h) * kS + i) * kS + j] = kScale * p;
    }
}

// ---------------- fused softmax + PV -> fp16 ---------------------------------
__global__ __launch_bounds__(256) void softmax_pv_kernel(
    const float* __restrict__ sc, const float* __restrict__ vf,
    unsigned short* __restrict__ attnb) {
  const int i = blockIdx.x, b = blockIdx.y, t = threadIdx.x;
  const int lane = t & 63, w = t >> 6;
  __shared__ float lw[kH][kS];
#pragma unroll
  for (int sg = 0; sg < 4; ++sg) {
    int idx = t + sg * 256;
    int hh = idx >> 7, jj = idx & 127;
    lw[hh][jj] = sc[(((size_t)b * kH + hh) * kS + i) * kS + jj];
  }
  __syncthreads();
#pragma unroll
  for (int rr = 0; rr < 2; ++rr) {
    int h = w * 2 + rr;
    float v0 = lw[h][lane], v1 = lw[h][lane + 64];
    float m = fmaxf(v0, v1);
#pragma unroll
    for (int o = 32; o; o >>= 1) m = fmaxf(m, __shfl_xor(m, o));
    float e0 = expf(v0 - m), e1 = expf(v1 - m);
    float s = e0 + e1;
#pragma unroll
    for (int o = 32; o; o >>= 1) s += __shfl_xor(s, o);
    float inv = 1.0f / s;
    lw[h][lane] = e0 * inv;
    lw[h][lane + 64] = e1 * inv;
  }
  __syncthreads();
  const float* vb = vf + (size_t)b * kS * kE;
  float s0 = 0.f, s1 = 0.f;
  for (int jj = 0; jj < kS; ++jj) {
    s0 += lw[w][jj] * vb[(size_t)jj * kE + t];
    s1 += lw[w + 4][jj] * vb[(size_t)jj * kE + t + 256];
  }
  size_t o = ((size_t)b * kS + i) * kE;
  attnb[o + t] = f2h(s0);
  attnb[o + t + 256] = f2h(s1);
}

// ---------------- final LN -> d_out ------------------------------------------
__global__ __launch_bounds__(256) void ln_out_kernel(
    const float* __restrict__ in, const float* __restrict__ st,
    const float* __restrict__ g, const float* __restrict__ bb,
    float* __restrict__ out) {
  int row = blockIdx.x, t = threadIdx.x;
  float mu, inv;
  ln_mu_inv(st, row, mu, inv);
#pragma unroll
  for (int half = 0; half < 2; ++half) {
    int c = t + half * 256;
    float v = in[(size_t)row * kE + c];
    out[(size_t)row * kE + c] = (v - mu) * inv * g[c] + bb[c];
  }
}

extern "C" void kernel_launch(void* const* d_in, const int* in_sizes, int n_in,
                              void* d_out, int out_size, void* d_ws, size_t ws_size,
                              hipStream_t stream) {
  (void)in_sizes; (void)n_in; (void)out_size; (void)ws_size;
  const float* x_in = (const float*)d_in[0];
  const float* rel  = (const float*)d_in[1];
  const float* Wq = (const float*)d_in[2];
  const float* bq = (const float*)d_in[3];
  const float* Wk = (const float*)d_in[4];
  const float* bk = (const float*)d_in[5];
  const float* Wv = (const float*)d_in[6];
  const float* bv = (const float*)d_in[7];
  const float* Wr = (const float*)d_in[8];
  const float* Wo = (const float*)d_in[9];
  const float* bo = (const float*)d_in[10];
  const float* W1 = (const float*)d_in[11];
  const float* b1 = (const float*)d_in[12];
  const float* W2 = (const float*)d_in[13];
  const float* b2 = (const float*)d_in[14];
  const float* ln1g = (const float*)d_in[15];
  const float* ln1b = (const float*)d_in[16];
  const float* ln2g = (const float*)d_in[17];
  const float* ln2b = (const float*)d_in[18];

  char* ws = (char*)d_ws;
  size_t off = 0;
  auto alloc = [&](size_t bytes) -> char* {
    char* p = ws + off;
    off += (bytes + 255) & ~(size_t)255;
    return p;
  };

  unsigned short* relb = (unsigned short*)alloc((size_t)kB * kS * kS * kE * 2);
  float* scores = (float*)alloc((size_t)kB * kH * kS * kS * 4);
  float* qf = (float*)alloc((size_t)kB * kS * kE * 4);
  float* kf = (float*)alloc((size_t)kB * kS * kE * 4);
  float* vf = (float*)alloc((size_t)kB * kS * kE * 4);
  unsigned short* curb = (unsigned short*)alloc((size_t)kB * kS * kE * 2);
  float* tmp1 = (float*)alloc((size_t)kB * kS * kE * 4);
  float* tmp2a = (float*)alloc((size_t)kB * kS * kE * 4);
  float* tmp2b = (float*)alloc((size_t)kB * kS * kE * 4);
  unsigned short* h1b = (unsigned short*)alloc((size_t)kB * kS * kF * 2);
  unsigned short* attnb = (unsigned short*)alloc((size_t)kB * kS * kE * 2);
  float* stats = (float*)alloc(4 * 512 * 4);  // 4 stages x (256 sum + 256 sumsq)
  unsigned short* wqkvT[2], *wrTl[2], *w1Tl[2], *w2Tl[2];
  for (int l = 0; l < 2; ++l) {
    wqkvT[l] = (unsigned short*)alloc((size_t)3 * kE * kE * 2);
    wrTl[l] = (unsigned short*)alloc((size_t)2 * kE * kE * 2);
    w1Tl[l] = (unsigned short*)alloc((size_t)kF * kE * 2);
    w2Tl[l] = (unsigned short*)alloc((size_t)kE * kF * 2);
  }
  unsigned short* woT0 = (unsigned short*)alloc((size_t)kE * kE * 2);
  unsigned short* woT1 = (unsigned short*)alloc((size_t)kE * kE * 2);

  int nGroups = kB * kS * kS * kE / 8;
  cast_swz_kernel<<<nGroups / 256, 256, 0, stream>>>(rel, relb, nGroups);
  initx_kernel<<<kB * kS * kE / 256, 256, 0, stream>>>(x_in, curb, stats);

  // all weight packs for both layers in ONE launch
  {
    const int t512 = (kE / 32) * (kE / 32);  // 256
    TArgs ta;
    int n = 0;
    for (int l = 0; l < 2; ++l) {
      ta.d[n++] = { Wq + (size_t)l * kE * kE, wqkvT[l], kE, kE, t512, 0 };
      ta.d[n++] = { Wk + (size_t)l * kE * kE, wqkvT[l] + (size_t)kE * kE, kE, kE, t512, 0 };
      ta.d[n++] = { Wv + (size_t)l * kE * kE, wqkvT[l] + (size_t)2 * kE * kE, kE, kE, t512, 0 };
      ta.d[n++] = { Wr + (size_t)l * kE * 2 * kE, wrTl[l], kE, 2 * kE, 2 * t512, 1 };
      ta.d[n++] = { W1 + (size_t)l * kE * kF, w1Tl[l], kE, kF, (kE / 32) * (kF / 32), 0 };
      ta.d[n++] = { W2 + (size_t)l * kF * kE, w2Tl[l], kF, kE, (kF / 32) * (kE / 32), 0 };
    }
    // Wo is NOT layer-indexed in the reference: batch b uses Wo[b] in BOTH layers.
    ta.d[n++] = { Wo, woT0, kE, kE, t512, 0 };
    ta.d[n++] = { Wo + (size_t)kE * kE, woT1, kE, kE, t512, 0 };
    ta.n = n;
    int total = 0;
    for (int i = 0; i < n; ++i) total += ta.d[i].tiles;
    transpose_pack_kernel<<<total, 256, 0, stream>>>(ta);
  }

  for (int l = 0; l < kL; ++l) {
    float* st1 = stats + (2 * l) * 512;        // LN1 stats of layer l
    float* st2 = stats + (2 * l + 1) * 512;    // LN2 stats of layer l
    const float* stPrev = stats + 512;         // LN2 stats of layer 0 (for l=1)
    float* tmp2 = (l == 0) ? tmp2a : tmp2b;

    if (l == 0)
      gemm_qkv<0><<<dim3(4, 3 * kE / 64), 256, 0, stream>>>(
          curb, nullptr, nullptr, nullptr, nullptr, wqkvT[l],
          bq, bk, bv, qf, kf, vf);
    else
      gemm_qkv<1><<<dim3(4, 3 * kE / 64), 256, 0, stream>>>(
          nullptr, tmp2a, stPrev, ln2g, ln2b, wqkvT[l],
          bq + (size_t)l * kE, bk + (size_t)l * kE, bv + (size_t)l * kE, qf, kf, vf);

    score_kernel<<<dim3(kS, kB, kH), 256, 0, stream>>>(relb, wrTl[l], qf, kf, scores);
    softmax_pv_kernel<<<dim3(kS, kB), 256, 0, stream>>>(scores, vf, attnb);

    if (l == 0)
      gemm_wo<0><<<dim3(4, kE / 64), 256, 0, stream>>>(
          attnb, woT0, woT1, bo, x_in, nullptr, nullptr, nullptr, nullptr, tmp1, st1);
    else
      gemm_wo<1><<<dim3(4, kE / 64), 256, 0, stream>>>(
          attnb, woT0, woT1, bo + (size_t)l * kE, nullptr, tmp2a, stPrev, ln2g, ln2b, tmp1, st1);

    gemm_ffn1<<<dim3(4, kF / 64), 256, 0, stream>>>(
        tmp1, st1, ln1g + (size_t)l * kE, ln1b + (size_t)l * kE,
        w1Tl[l], b1 + (size_t)l * kF, h1b);
    gemm_ffn2<<<dim3(4, kE / 64), 256, 0, stream>>>(
        h1b, w2Tl[l], b2 + (size_t)l * kE, tmp1,
        st1, ln1g + (size_t)l * kE, ln1b + (size_t)l * kE, tmp2, st2);
  }

  ln_out_kernel<<<kB * kS, 256, 0, stream>>>(
      tmp2b, stats + 3 * 512, ln2g + (size_t)kE, ln2b + (size_t)kE, (float*)d_out);
}